// Round 7
// baseline (327.786 us; speedup 1.0000x reference)
//
#include <hip/hip_runtime.h>
#include <math.h>

// Pruned-cone evaluation of the 2-hop GATv2 dependency cone of the query asset.
// R7: 6-dispatch chain. No flag arrays (list-append frontier w/ benign dups,
// per-L2-edge slot recorded at append time) -> memset is 64 B. int4-vectorized
// edge scans. Layer-2 + classifier head fused into one single-block kernel.
#define FAMAX 64     // asset frontier slots (expected ~10 incl dups + q)
#define FCMAX 32
#define FLMAX 32
#define N1MAX 512    // layer-1 edges into frontier (expected ~160 incl dups)
#define N2MAX 128    // layer-2 edges into query (expected ~9)
#define XL2C  24     // LDS cache for per-L2-edge xl2 columns

struct Inputs {
  const float *x_asset, *x_creator, *x_licensee;
  const float *Wp_a,*bp_a,*Wp_c,*bp_c,*Wp_l,*bp_l;
  const float *Wl1,*bl1,*Wr1,*br1,*We1,*att1,*bias1;
  const float *Wl2,*bl2,*Wr2,*br2,*We2,*att2,*bias2;
  const float *Wc1,*bc1,*Wc2,*bc2;
};

struct Edges {
  const int *cb_s,*cb_d;  const float* ea_cb;  int Ecb;
  const int *lt_s,*lt_d;  const float* ea_lt;  int Elt;
  const int *sim_s,*sim_d;const float* ea_sim; int Esim;
  const int *fw_s,*fw_d;  const float* ea_fw;  int Efw;
  const int *rcb_s,*rcb_d;const float* ea_rcb; int Ercb;
  const int *rlt_s,*rlt_d;const float* ea_rlt; int Erlt;
};

struct WSP {
  int* cnt;   // [0]=n_l2e [1]=nfa [2]=nfc [3]=nfl [4]=n_l1e [5]=qslot  (64 B zeroed)
  int *fa,*fc,*fl;            // frontier node ids (dups allowed)
  int* l2rel; int* l2src; int* l2slot; float* l2ea;
  int* l1rel; int* l1src; int* l1dslot; float* l1ea;
  float* xl1e;                // [N1MAX][256]
  float* logit1;              // [N1MAX][2]
  float *x1a,*x1c,*x1l;       // layer-1 outputs per slot [.][128]
  float* xl2e;                // [N2MAX][128] spill (only if n2 > XL2C)
};

__device__ __forceinline__ float leaky(float x){ return x > 0.f ? x : 0.2f*x; }

// 128-d input projection of `node` of `type` into LDS h0[], 256 threads.
__device__ __forceinline__ void proj256(int type, int node, const Inputs& in,
                                        float* h0, float* xs, float* part){
  int t = threadIdx.x;
  if (type == 0){
    xs[t]       = in.x_asset[(size_t)node*512 + t];
    xs[t + 256] = in.x_asset[(size_t)node*512 + t + 256];
    __syncthreads();
    int j = t & 127, g2 = t >> 7;
    float acc = 0.f;
    const float* W = in.Wp_a + (size_t)g2*256*128 + j;
    const float* xg = xs + g2*256;
    for (int k=0;k<256;k++) acc = fmaf(xg[k], W[(size_t)k*128], acc);
    part[t] = acc;
    __syncthreads();
    if (t < 128) h0[t] = in.bp_a[t] + part[t] + part[128 + t];
  } else if (type == 1){
    if (t < 128)
      h0[t] = in.bp_c[t] + in.x_creator[node*2]*in.Wp_c[t]
            + in.x_creator[node*2+1]*in.Wp_c[128+t];
  } else {
    if (t < 128)
      h0[t] = in.bp_l[t] + in.x_licensee[node]*in.Wp_l[t];
  }
  __syncthreads();
}

// K1: int4 scan of Asset-targeting relations for dst == q.
// Appends L2 edges; appends srcs to frontier lists (no dedup); records slot per edge.
__global__ void k1_scan_l2(Edges eg, const int* qptr, WSP w){
  int q = qptr[0];
  if (blockIdx.x==0 && threadIdx.x==0){
    int s = atomicAdd(&w.cnt[1], 1);
    if (s < FAMAX){ w.fa[s] = q; w.cnt[5] = s; } else w.cnt[5] = 0;
  }
  int total4 = (eg.Esim + eg.Efw + eg.Ercb + eg.Erlt) >> 2;
  for (int i4 = blockIdx.x*blockDim.x + threadIdx.x; i4 < total4; i4 += gridDim.x*blockDim.x){
    int j = i4 << 2, rel; const int *sp,*dp; const float* ep;
    if (j < eg.Esim){ rel=2; sp=eg.sim_s; dp=eg.sim_d; ep=eg.ea_sim; }
    else { j -= eg.Esim;
      if (j < eg.Efw){ rel=3; sp=eg.fw_s; dp=eg.fw_d; ep=eg.ea_fw; }
      else { j -= eg.Efw;
        if (j < eg.Ercb){ rel=4; sp=eg.rcb_s; dp=eg.rcb_d; ep=eg.ea_rcb; }
        else { j -= eg.Ercb; rel=5; sp=eg.rlt_s; dp=eg.rlt_d; ep=eg.ea_rlt; }
      }
    }
    int4 d4 = *(const int4*)(dp + j);
    #pragma unroll
    for (int m=0;m<4;m++){
      int d = (m==0)?d4.x:(m==1)?d4.y:(m==2)?d4.z:d4.w;
      if (d == q){
        int src = sp[j+m];
        int k = atomicAdd(&w.cnt[0], 1);
        if (k < N2MAX){
          w.l2rel[k]=rel; w.l2src[k]=src; w.l2ea[k]=ep[j+m];
          int s, slot = -1;
          if (rel <= 3){ s = atomicAdd(&w.cnt[1],1); if (s<FAMAX){ w.fa[s]=src; slot=s; } }
          else if (rel == 4){ s = atomicAdd(&w.cnt[2],1); if (s<FCMAX){ w.fc[s]=src; slot=s; } }
          else { s = atomicAdd(&w.cnt[3],1); if (s<FLMAX){ w.fl[s]=src; slot=s; } }
          w.l2slot[k] = slot;
        }
      }
    }
  }
}

// K2: int4 scan of all 6 relations; membership test vs LDS frontier lists.
__global__ void k2_scan_l1(Edges eg, WSP w){
  __shared__ int sfa[FAMAX], sfc[FCMAX], sfl[FLMAX];
  __shared__ int snf[3];
  int t = threadIdx.x;
  if (t < 3){
    int caps[3] = {FAMAX, FCMAX, FLMAX};
    int v = w.cnt[1+t]; snf[t] = v < caps[t] ? v : caps[t];
  }
  if (t < FAMAX) sfa[t] = w.fa[t];
  if (t < FCMAX) sfc[t] = w.fc[t];
  if (t < FLMAX) sfl[t] = w.fl[t];
  __syncthreads();
  int total4 = (eg.Ecb+eg.Elt+eg.Esim+eg.Efw+eg.Ercb+eg.Erlt) >> 2;
  for (int i4 = blockIdx.x*blockDim.x + t; i4 < total4; i4 += gridDim.x*blockDim.x){
    int j = i4 << 2, rel; const int *sp,*dp; const float* ep;
    if (j < eg.Ecb){ rel=0; sp=eg.cb_s; dp=eg.cb_d; ep=eg.ea_cb; }
    else { j -= eg.Ecb;
    if (j < eg.Elt){ rel=1; sp=eg.lt_s; dp=eg.lt_d; ep=eg.ea_lt; }
    else { j -= eg.Elt;
    if (j < eg.Esim){ rel=2; sp=eg.sim_s; dp=eg.sim_d; ep=eg.ea_sim; }
    else { j -= eg.Esim;
    if (j < eg.Efw){ rel=3; sp=eg.fw_s; dp=eg.fw_d; ep=eg.ea_fw; }
    else { j -= eg.Efw;
    if (j < eg.Ercb){ rel=4; sp=eg.rcb_s; dp=eg.rcb_d; ep=eg.ea_rcb; }
    else { j -= eg.Ercb; rel=5; sp=eg.rlt_s; dp=eg.rlt_d; ep=eg.ea_rlt; }}}}}
    const int* lst = (rel==0) ? sfc : (rel==1) ? sfl : sfa;
    int n = (rel==0) ? snf[1] : (rel==1) ? snf[2] : snf[0];
    int4 d4 = *(const int4*)(dp + j);
    #pragma unroll
    for (int m=0;m<4;m++){
      int d = (m==0)?d4.x:(m==1)?d4.y:(m==2)?d4.z:d4.w;
      for (int s=0;s<n;s++){
        if (d == lst[s]){
          int k = atomicAdd(&w.cnt[4], 1);
          if (k < N1MAX){ w.l1rel[k]=rel; w.l1src[k]=sp[j+m]; w.l1dslot[k]=s; w.l1ea[k]=ep[j+m]; }
        }
      }
    }
  }
}

// K3: per L1 edge (256 thr): proj(src)->xl1 (stored), proj(dst)->xr1 (local),
// attention logits per head via block reduce.
__global__ void k3_edge(Inputs in, WSP w){
  __shared__ float xs[512];
  __shared__ float part[256];
  __shared__ float h0s[128];
  __shared__ float h0d[128];
  __shared__ float red[256];
  int i = blockIdx.x, t = threadIdx.x;
  int n1 = w.cnt[4] < N1MAX ? w.cnt[4] : N1MAX;
  if (i >= n1) return;
  int rel = w.l1rel[i], src = w.l1src[i], dslot = w.l1dslot[i];
  float ea = w.l1ea[i];
  int stype = (rel <= 3) ? 0 : (rel == 4 ? 1 : 2);
  int dtype = (rel == 0) ? 1 : (rel == 1 ? 2 : 0);
  int dnode = (rel == 0) ? w.fc[dslot] : (rel == 1 ? w.fl[dslot] : w.fa[dslot]);
  proj256(stype, src, in, h0s, xs, part);
  float xl1 = in.bl1[rel*256 + t];
  {
    const float* W = in.Wl1 + (size_t)rel*128*256 + t;
    for (int c=0;c<128;c++) xl1 = fmaf(h0s[c], W[(size_t)c*256], xl1);
  }
  w.xl1e[(size_t)i*256 + t] = xl1;
  proj256(dtype, dnode, in, h0d, xs, part);
  float xr1 = in.br1[rel*256 + t];
  {
    const float* W = in.Wr1 + (size_t)rel*128*256 + t;
    for (int c=0;c<128;c++) xr1 = fmaf(h0d[c], W[(size_t)c*256], xr1);
  }
  int h = t >> 7, c = t & 127;
  float e = leaky(xl1 + xr1 + ea*in.We1[rel*256 + t]);
  red[t] = e * in.att1[(rel*2 + h)*128 + c];
  __syncthreads();
  for (int s=64; s>0; s>>=1){ if (c < s) red[t] += red[t+s]; __syncthreads(); }
  if (c == 0) w.logit1[i*2 + h] = red[t];
}

// K4: per frontier slot (128 thr): segment softmax + aggregate -> x1.
__global__ void k4_agg(Inputs in, WSP w){
  int b = blockIdx.x, j = threadIdx.x;
  int nfa = w.cnt[1] < FAMAX ? w.cnt[1] : FAMAX;
  int nfc = w.cnt[2] < FCMAX ? w.cnt[2] : FCMAX;
  int nfl = w.cnt[3] < FLMAX ? w.cnt[3] : FLMAX;
  int type, slot;
  if (b < FAMAX){ slot=b; if (slot>=nfa) return; type=0; }
  else if (b < FAMAX+FCMAX){ slot=b-FAMAX; if (slot>=nfc) return; type=1; }
  else { slot=b-FAMAX-FCMAX; if (slot>=nfl) return; type=2; }
  int n1 = w.cnt[4] < N1MAX ? w.cnt[4] : N1MAX;
  float out = 0.f;
  int r0, r1;
  if (type==0){ r0=2; r1=5; } else if (type==1){ r0=0; r1=0; } else { r0=1; r1=1; }
  for (int r=r0; r<=r1; r++){
    out += in.bias1[r*128 + j];
    float m0=-INFINITY, m1=-INFINITY;
    for (int i=0;i<n1;i++){
      if (w.l1rel[i]==r && w.l1dslot[i]==slot){
        m0 = fmaxf(m0, w.logit1[i*2]);
        m1 = fmaxf(m1, w.logit1[i*2+1]);
      }
    }
    if (m0 == -INFINITY) continue;
    float d0=0.f, d1=0.f, a0=0.f, a1=0.f;
    for (int i=0;i<n1;i++){
      if (w.l1rel[i]==r && w.l1dslot[i]==slot){
        float e0 = expf(w.logit1[i*2]   - m0);
        float e1 = expf(w.logit1[i*2+1] - m1);
        d0 += e0; d1 += e1;
        a0 = fmaf(e0, w.xl1e[(size_t)i*256 + j],       a0);
        a1 = fmaf(e1, w.xl1e[(size_t)i*256 + 128 + j], a1);
      }
    }
    out += 0.5f*(a0/(d0+1e-16f) + a1/(d1+1e-16f));
  }
  float v = fmaxf(out, 0.f);
  if (type==0) w.x1a[slot*128 + j] = v;
  else if (type==1) w.x1c[slot*128 + j] = v;
  else w.x1l[slot*128 + j] = v;
}

// K5: single block (256 thr): xr2 (4 rels), per-L2-edge xl2+logit (xl2 in LDS,
// spill to global past XL2C), segment softmax + aggregate + relu, classifier head.
__global__ void k5_final(Inputs in, WSP w, float* outp){
  __shared__ float xq[128];
  __shared__ float xsrc[128];
  __shared__ float xr2s[4][128];
  __shared__ float xl2s[XL2C][128];
  __shared__ float red[128];
  __shared__ float lg2[N2MAX];
  __shared__ int   srl2[N2MAX];
  __shared__ float x2[128];
  __shared__ float tt[128];
  int t = threadIdx.x, j = t & 127, half = t >> 7;
  int n2 = w.cnt[0] < N2MAX ? w.cnt[0] : N2MAX;
  int qs = w.cnt[5]; if (qs >= FAMAX) qs = 0;
  if (t < 128) xq[t] = w.x1a[(size_t)qs*128 + t];
  __syncthreads();
  for (int rr = half; rr < 4; rr += 2){
    int r = 2 + rr;
    float acc = in.br2[r*128 + j];
    const float* W = in.Wr2 + (size_t)r*128*128 + j;
    for (int c=0;c<128;c++) acc = fmaf(xq[c], W[(size_t)c*128], acc);
    xr2s[rr][j] = acc;
  }
  __syncthreads();
  for (int i=0;i<n2;i++){
    int rel = w.l2rel[i], slot = w.l2slot[i];
    if (slot < 0){ if (t==0) srl2[i] = -1; __syncthreads(); continue; }
    const float* xb = (rel<=3) ? w.x1a : (rel==4 ? w.x1c : w.x1l);
    if (t < 128) xsrc[t] = xb[(size_t)slot*128 + t];
    __syncthreads();
    if (t < 128){
      float xl2 = in.bl2[rel*128 + t];
      const float* W = in.Wl2 + (size_t)rel*128*128 + t;
      for (int c=0;c<128;c++) xl2 = fmaf(xsrc[c], W[(size_t)c*128], xl2);
      if (i < XL2C) xl2s[i][t] = xl2;
      else w.xl2e[(size_t)i*128 + t] = xl2;
      float e = leaky(xl2 + xr2s[rel-2][t] + w.l2ea[i]*in.We2[rel*128 + t]);
      red[t] = e * in.att2[rel*128 + t];
    }
    __syncthreads();
    for (int s=64; s>0; s>>=1){ if (t < s) red[t] += red[t+s]; __syncthreads(); }
    if (t == 0){ lg2[i] = red[0]; srl2[i] = rel; }
    __syncthreads();
  }
  if (t < 128){
    float o = 0.f;
    for (int r=2; r<=5; r++){
      o += in.bias2[r*128 + t];
      float m = -INFINITY;
      for (int i=0;i<n2;i++) if (srl2[i]==r) m = fmaxf(m, lg2[i]);
      if (m == -INFINITY) continue;
      float d = 0.f, acc = 0.f;
      for (int i=0;i<n2;i++) if (srl2[i]==r){
        float e = expf(lg2[i] - m);
        d += e;
        float xv = (i < XL2C) ? xl2s[i][t] : w.xl2e[(size_t)i*128 + t];
        acc = fmaf(e, xv, acc);
      }
      o += acc/(d + 1e-16f);
    }
    x2[t] = fmaxf(o, 0.f);
  }
  __syncthreads();
  if (t < 128){
    float acc = in.bc1[t];
    for (int c=0;c<128;c++) acc = fmaf(x2[c], in.Wc1[c*128 + t], acc);
    tt[t] = fmaxf(acc, 0.f);
  }
  __syncthreads();
  if (t < 3){
    float r = in.bc2[t];
    for (int c=0;c<128;c++) r = fmaf(tt[c], in.Wc2[c*3 + t], r);
    outp[t] = r;
  }
}

extern "C" void kernel_launch(void* const* d_in, const int* in_sizes, int n_in,
                              void* d_out, int out_size, void* d_ws, size_t ws_size,
                              hipStream_t stream){
  Inputs in;
  in.x_asset   = (const float*)d_in[0];
  in.x_creator = (const float*)d_in[1];
  in.x_licensee= (const float*)d_in[2];
  Edges eg;
  eg.cb_s =(const int*)d_in[3];  eg.cb_d =(const int*)d_in[4];  eg.ea_cb =(const float*)d_in[5];  eg.Ecb = in_sizes[3];
  eg.lt_s =(const int*)d_in[6];  eg.lt_d =(const int*)d_in[7];  eg.ea_lt =(const float*)d_in[8];  eg.Elt = in_sizes[6];
  eg.sim_s=(const int*)d_in[9];  eg.sim_d=(const int*)d_in[10]; eg.ea_sim=(const float*)d_in[11]; eg.Esim= in_sizes[9];
  eg.fw_s =(const int*)d_in[12]; eg.fw_d =(const int*)d_in[13]; eg.ea_fw =(const float*)d_in[14]; eg.Efw = in_sizes[12];
  eg.rcb_s=(const int*)d_in[15]; eg.rcb_d=(const int*)d_in[16]; eg.ea_rcb=(const float*)d_in[17]; eg.Ercb= in_sizes[15];
  eg.rlt_s=(const int*)d_in[18]; eg.rlt_d=(const int*)d_in[19]; eg.ea_rlt=(const float*)d_in[20]; eg.Erlt= in_sizes[18];
  in.Wp_a=(const float*)d_in[21]; in.bp_a=(const float*)d_in[22];
  in.Wp_c=(const float*)d_in[23]; in.bp_c=(const float*)d_in[24];
  in.Wp_l=(const float*)d_in[25]; in.bp_l=(const float*)d_in[26];
  in.Wl1=(const float*)d_in[27]; in.bl1=(const float*)d_in[28];
  in.Wr1=(const float*)d_in[29]; in.br1=(const float*)d_in[30];
  in.We1=(const float*)d_in[31]; in.att1=(const float*)d_in[32]; in.bias1=(const float*)d_in[33];
  in.Wl2=(const float*)d_in[34]; in.bl2=(const float*)d_in[35];
  in.Wr2=(const float*)d_in[36]; in.br2=(const float*)d_in[37];
  in.We2=(const float*)d_in[38]; in.att2=(const float*)d_in[39]; in.bias2=(const float*)d_in[40];
  in.Wc1=(const float*)d_in[41]; in.bc1=(const float*)d_in[42];
  in.Wc2=(const float*)d_in[43]; in.bc2=(const float*)d_in[44];
  const int* qptr = (const int*)d_in[45];

  char* p = (char*)d_ws;
  auto carve = [&](size_t n)->char*{ char* r = p; p += ((n + 255) & ~(size_t)255); return r; };
  WSP w;
  w.cnt  = (int*)carve(16*4);
  w.fa = (int*)carve(FAMAX*4); w.fc = (int*)carve(FCMAX*4); w.fl = (int*)carve(FLMAX*4);
  w.l2rel=(int*)carve(N2MAX*4); w.l2src=(int*)carve(N2MAX*4); w.l2slot=(int*)carve(N2MAX*4); w.l2ea=(float*)carve(N2MAX*4);
  w.l1rel=(int*)carve(N1MAX*4); w.l1src=(int*)carve(N1MAX*4); w.l1dslot=(int*)carve(N1MAX*4); w.l1ea=(float*)carve(N1MAX*4);
  w.xl1e=(float*)carve((size_t)N1MAX*256*4);
  w.logit1=(float*)carve((size_t)N1MAX*2*4);
  w.x1a=(float*)carve((size_t)FAMAX*128*4);
  w.x1c=(float*)carve((size_t)FCMAX*128*4);
  w.x1l=(float*)carve((size_t)FLMAX*128*4);
  w.xl2e=(float*)carve((size_t)N2MAX*128*4);

  hipMemsetAsync(w.cnt, 0, 16*4, stream);

  int tE2_4 = (eg.Esim + eg.Efw + eg.Ercb + eg.Erlt) >> 2;
  k1_scan_l2<<<(tE2_4+255)/256, 256, 0, stream>>>(eg, qptr, w);
  int tE1_4 = (eg.Ecb + eg.Elt + eg.Esim + eg.Efw + eg.Ercb + eg.Erlt) >> 2;
  k2_scan_l1<<<(tE1_4+255)/256, 256, 0, stream>>>(eg, w);
  k3_edge<<<N1MAX, 256, 0, stream>>>(in, w);
  k4_agg<<<FAMAX + FCMAX + FLMAX, 128, 0, stream>>>(in, w);
  k5_final<<<1, 256, 0, stream>>>(in, w, (float*)d_out);
}

// Round 8
// 309.225 us; speedup vs baseline: 1.0600x; 1.0600x over previous
//
#include <hip/hip_runtime.h>
#include <math.h>

// Pruned-cone evaluation of the 2-hop GATv2 dependency cone of the query asset.
// R8 = R7 front-end (64B memset, int4 scans, list-append frontier w/ benign
// dups) + R6 back-end (layer-2 split across blocks; tiny final block).
// Rule learned R2/R7: never put weight-matrix matvecs in a single block.
#define FAMAX 64     // asset frontier slots (expected ~10 incl dups + q)
#define FCMAX 32
#define FLMAX 32
#define N1MAX 512    // layer-1 edges into frontier (expected ~160 incl dups)
#define N2MAX 128    // layer-2 edges into query (expected ~9)

struct Inputs {
  const float *x_asset, *x_creator, *x_licensee;
  const float *Wp_a,*bp_a,*Wp_c,*bp_c,*Wp_l,*bp_l;
  const float *Wl1,*bl1,*Wr1,*br1,*We1,*att1,*bias1;
  const float *Wl2,*bl2,*Wr2,*br2,*We2,*att2,*bias2;
  const float *Wc1,*bc1,*Wc2,*bc2;
};

struct Edges {
  const int *cb_s,*cb_d;  const float* ea_cb;  int Ecb;
  const int *lt_s,*lt_d;  const float* ea_lt;  int Elt;
  const int *sim_s,*sim_d;const float* ea_sim; int Esim;
  const int *fw_s,*fw_d;  const float* ea_fw;  int Efw;
  const int *rcb_s,*rcb_d;const float* ea_rcb; int Ercb;
  const int *rlt_s,*rlt_d;const float* ea_rlt; int Erlt;
};

struct WSP {
  int* cnt;   // [0]=n_l2e [1]=nfa [2]=nfc [3]=nfl [4]=n_l1e [5]=qslot  (64 B zeroed)
  int *fa,*fc,*fl;            // frontier node ids (dups allowed)
  int* l2rel; int* l2src; int* l2slot; float* l2ea;
  int* l1rel; int* l1src; int* l1dslot; float* l1ea;
  float* xl1e;                // [N1MAX][256]
  float* logit1;              // [N1MAX][2]
  float *x1a,*x1c,*x1l;       // layer-1 outputs per slot [.][128]
  float* xl2e;                // [N2MAX][128]
  float* logit2;              // [N2MAX]
};

__device__ __forceinline__ float leaky(float x){ return x > 0.f ? x : 0.2f*x; }

// 128-d input projection of `node` of `type` into LDS h0[], 256 threads.
__device__ __forceinline__ void proj256(int type, int node, const Inputs& in,
                                        float* h0, float* xs, float* part){
  int t = threadIdx.x;
  if (type == 0){
    xs[t]       = in.x_asset[(size_t)node*512 + t];
    xs[t + 256] = in.x_asset[(size_t)node*512 + t + 256];
    __syncthreads();
    int j = t & 127, g2 = t >> 7;
    float acc = 0.f;
    const float* W = in.Wp_a + (size_t)g2*256*128 + j;
    const float* xg = xs + g2*256;
    for (int k=0;k<256;k++) acc = fmaf(xg[k], W[(size_t)k*128], acc);
    part[t] = acc;
    __syncthreads();
    if (t < 128) h0[t] = in.bp_a[t] + part[t] + part[128 + t];
  } else if (type == 1){
    if (t < 128)
      h0[t] = in.bp_c[t] + in.x_creator[node*2]*in.Wp_c[t]
            + in.x_creator[node*2+1]*in.Wp_c[128+t];
  } else {
    if (t < 128)
      h0[t] = in.bp_l[t] + in.x_licensee[node]*in.Wp_l[t];
  }
  __syncthreads();
}

// K1: int4 scan of Asset-targeting relations for dst == q.
// Appends L2 edges; appends srcs to frontier lists (no dedup); records slot per edge.
__global__ void k1_scan_l2(Edges eg, const int* qptr, WSP w){
  int q = qptr[0];
  if (blockIdx.x==0 && threadIdx.x==0){
    int s = atomicAdd(&w.cnt[1], 1);
    if (s < FAMAX){ w.fa[s] = q; w.cnt[5] = s; } else w.cnt[5] = 0;
  }
  int total4 = (eg.Esim + eg.Efw + eg.Ercb + eg.Erlt) >> 2;
  for (int i4 = blockIdx.x*blockDim.x + threadIdx.x; i4 < total4; i4 += gridDim.x*blockDim.x){
    int j = i4 << 2, rel; const int *sp,*dp; const float* ep;
    if (j < eg.Esim){ rel=2; sp=eg.sim_s; dp=eg.sim_d; ep=eg.ea_sim; }
    else { j -= eg.Esim;
      if (j < eg.Efw){ rel=3; sp=eg.fw_s; dp=eg.fw_d; ep=eg.ea_fw; }
      else { j -= eg.Efw;
        if (j < eg.Ercb){ rel=4; sp=eg.rcb_s; dp=eg.rcb_d; ep=eg.ea_rcb; }
        else { j -= eg.Ercb; rel=5; sp=eg.rlt_s; dp=eg.rlt_d; ep=eg.ea_rlt; }
      }
    }
    int4 d4 = *(const int4*)(dp + j);
    #pragma unroll
    for (int m=0;m<4;m++){
      int d = (m==0)?d4.x:(m==1)?d4.y:(m==2)?d4.z:d4.w;
      if (d == q){
        int src = sp[j+m];
        int k = atomicAdd(&w.cnt[0], 1);
        if (k < N2MAX){
          w.l2rel[k]=rel; w.l2src[k]=src; w.l2ea[k]=ep[j+m];
          int s, slot = -1;
          if (rel <= 3){ s = atomicAdd(&w.cnt[1],1); if (s<FAMAX){ w.fa[s]=src; slot=s; } }
          else if (rel == 4){ s = atomicAdd(&w.cnt[2],1); if (s<FCMAX){ w.fc[s]=src; slot=s; } }
          else { s = atomicAdd(&w.cnt[3],1); if (s<FLMAX){ w.fl[s]=src; slot=s; } }
          w.l2slot[k] = slot;
        }
      }
    }
  }
}

// K2: int4 scan of all 6 relations; membership test vs LDS frontier lists.
__global__ void k2_scan_l1(Edges eg, WSP w){
  __shared__ int sfa[FAMAX], sfc[FCMAX], sfl[FLMAX];
  __shared__ int snf[3];
  int t = threadIdx.x;
  if (t < 3){
    int caps[3] = {FAMAX, FCMAX, FLMAX};
    int v = w.cnt[1+t]; snf[t] = v < caps[t] ? v : caps[t];
  }
  if (t < FAMAX) sfa[t] = w.fa[t];
  if (t < FCMAX) sfc[t] = w.fc[t];
  if (t < FLMAX) sfl[t] = w.fl[t];
  __syncthreads();
  int total4 = (eg.Ecb+eg.Elt+eg.Esim+eg.Efw+eg.Ercb+eg.Erlt) >> 2;
  for (int i4 = blockIdx.x*blockDim.x + t; i4 < total4; i4 += gridDim.x*blockDim.x){
    int j = i4 << 2, rel; const int *sp,*dp; const float* ep;
    if (j < eg.Ecb){ rel=0; sp=eg.cb_s; dp=eg.cb_d; ep=eg.ea_cb; }
    else { j -= eg.Ecb;
    if (j < eg.Elt){ rel=1; sp=eg.lt_s; dp=eg.lt_d; ep=eg.ea_lt; }
    else { j -= eg.Elt;
    if (j < eg.Esim){ rel=2; sp=eg.sim_s; dp=eg.sim_d; ep=eg.ea_sim; }
    else { j -= eg.Esim;
    if (j < eg.Efw){ rel=3; sp=eg.fw_s; dp=eg.fw_d; ep=eg.ea_fw; }
    else { j -= eg.Efw;
    if (j < eg.Ercb){ rel=4; sp=eg.rcb_s; dp=eg.rcb_d; ep=eg.ea_rcb; }
    else { j -= eg.Ercb; rel=5; sp=eg.rlt_s; dp=eg.rlt_d; ep=eg.ea_rlt; }}}}}
    const int* lst = (rel==0) ? sfc : (rel==1) ? sfl : sfa;
    int n = (rel==0) ? snf[1] : (rel==1) ? snf[2] : snf[0];
    int4 d4 = *(const int4*)(dp + j);
    #pragma unroll
    for (int m=0;m<4;m++){
      int d = (m==0)?d4.x:(m==1)?d4.y:(m==2)?d4.z:d4.w;
      for (int s=0;s<n;s++){
        if (d == lst[s]){
          int k = atomicAdd(&w.cnt[4], 1);
          if (k < N1MAX){ w.l1rel[k]=rel; w.l1src[k]=sp[j+m]; w.l1dslot[k]=s; w.l1ea[k]=ep[j+m]; }
        }
      }
    }
  }
}

// K3: per L1 edge (256 thr): proj(src)->xl1 (stored), proj(dst)->xr1 (local),
// attention logits per head via block reduce.
__global__ void k3_edge(Inputs in, WSP w){
  __shared__ float xs[512];
  __shared__ float part[256];
  __shared__ float h0s[128];
  __shared__ float h0d[128];
  __shared__ float red[256];
  int i = blockIdx.x, t = threadIdx.x;
  int n1 = w.cnt[4] < N1MAX ? w.cnt[4] : N1MAX;
  if (i >= n1) return;
  int rel = w.l1rel[i], src = w.l1src[i], dslot = w.l1dslot[i];
  float ea = w.l1ea[i];
  int stype = (rel <= 3) ? 0 : (rel == 4 ? 1 : 2);
  int dtype = (rel == 0) ? 1 : (rel == 1 ? 2 : 0);
  int dnode = (rel == 0) ? w.fc[dslot] : (rel == 1 ? w.fl[dslot] : w.fa[dslot]);
  proj256(stype, src, in, h0s, xs, part);
  float xl1 = in.bl1[rel*256 + t];
  {
    const float* W = in.Wl1 + (size_t)rel*128*256 + t;
    for (int c=0;c<128;c++) xl1 = fmaf(h0s[c], W[(size_t)c*256], xl1);
  }
  w.xl1e[(size_t)i*256 + t] = xl1;
  proj256(dtype, dnode, in, h0d, xs, part);
  float xr1 = in.br1[rel*256 + t];
  {
    const float* W = in.Wr1 + (size_t)rel*128*256 + t;
    for (int c=0;c<128;c++) xr1 = fmaf(h0d[c], W[(size_t)c*256], xr1);
  }
  int h = t >> 7, c = t & 127;
  float e = leaky(xl1 + xr1 + ea*in.We1[rel*256 + t]);
  red[t] = e * in.att1[(rel*2 + h)*128 + c];
  __syncthreads();
  for (int s=64; s>0; s>>=1){ if (c < s) red[t] += red[t+s]; __syncthreads(); }
  if (c == 0) w.logit1[i*2 + h] = red[t];
}

// K4: per frontier slot (128 thr): segment softmax + aggregate -> x1.
__global__ void k4_agg(Inputs in, WSP w){
  int b = blockIdx.x, j = threadIdx.x;
  int nfa = w.cnt[1] < FAMAX ? w.cnt[1] : FAMAX;
  int nfc = w.cnt[2] < FCMAX ? w.cnt[2] : FCMAX;
  int nfl = w.cnt[3] < FLMAX ? w.cnt[3] : FLMAX;
  int type, slot;
  if (b < FAMAX){ slot=b; if (slot>=nfa) return; type=0; }
  else if (b < FAMAX+FCMAX){ slot=b-FAMAX; if (slot>=nfc) return; type=1; }
  else { slot=b-FAMAX-FCMAX; if (slot>=nfl) return; type=2; }
  int n1 = w.cnt[4] < N1MAX ? w.cnt[4] : N1MAX;
  float out = 0.f;
  int r0, r1;
  if (type==0){ r0=2; r1=5; } else if (type==1){ r0=0; r1=0; } else { r0=1; r1=1; }
  for (int r=r0; r<=r1; r++){
    out += in.bias1[r*128 + j];
    float m0=-INFINITY, m1=-INFINITY;
    for (int i=0;i<n1;i++){
      if (w.l1rel[i]==r && w.l1dslot[i]==slot){
        m0 = fmaxf(m0, w.logit1[i*2]);
        m1 = fmaxf(m1, w.logit1[i*2+1]);
      }
    }
    if (m0 == -INFINITY) continue;
    float d0=0.f, d1=0.f, a0=0.f, a1=0.f;
    for (int i=0;i<n1;i++){
      if (w.l1rel[i]==r && w.l1dslot[i]==slot){
        float e0 = expf(w.logit1[i*2]   - m0);
        float e1 = expf(w.logit1[i*2+1] - m1);
        d0 += e0; d1 += e1;
        a0 = fmaf(e0, w.xl1e[(size_t)i*256 + j],       a0);
        a1 = fmaf(e1, w.xl1e[(size_t)i*256 + 128 + j], a1);
      }
    }
    out += 0.5f*(a0/(d0+1e-16f) + a1/(d1+1e-16f));
  }
  float v = fmaxf(out, 0.f);
  if (type==0) w.x1a[slot*128 + j] = v;
  else if (type==1) w.x1c[slot*128 + j] = v;
  else w.x1l[slot*128 + j] = v;
}

// K5b: per L2 edge (128 thr): xr2 (inline for its relation) + xl2 + logit.
// Weight reads stay parallel across edge blocks (R2/R7 lesson).
__global__ void k5b_l2edge(Inputs in, WSP w){
  __shared__ float xq[128];
  __shared__ float xsrc[128];
  __shared__ float red[128];
  int i = blockIdx.x, j = threadIdx.x;
  int n2 = w.cnt[0] < N2MAX ? w.cnt[0] : N2MAX;
  if (i >= n2) return;
  int rel = w.l2rel[i], slot = w.l2slot[i];
  float ea = w.l2ea[i];
  if (slot < 0){  // frontier-capacity overflow guard
    w.xl2e[(size_t)i*128 + j] = 0.f;
    if (j == 0) w.logit2[i] = -INFINITY;
    return;
  }
  const float* xb = (rel<=3) ? w.x1a : (rel==4 ? w.x1c : w.x1l);
  int qs = w.cnt[5]; if (qs >= FAMAX) qs = 0;
  xq[j]   = w.x1a[(size_t)qs*128 + j];
  xsrc[j] = xb[(size_t)slot*128 + j];
  __syncthreads();
  float xr2 = in.br2[rel*128 + j];
  {
    const float* W = in.Wr2 + (size_t)rel*128*128 + j;
    for (int c=0;c<128;c++) xr2 = fmaf(xq[c], W[(size_t)c*128], xr2);
  }
  float xl2 = in.bl2[rel*128 + j];
  {
    const float* W = in.Wl2 + (size_t)rel*128*128 + j;
    for (int c=0;c<128;c++) xl2 = fmaf(xsrc[c], W[(size_t)c*128], xl2);
  }
  w.xl2e[(size_t)i*128 + j] = xl2;
  float e = leaky(xl2 + xr2 + ea*in.We2[rel*128 + j]);
  red[j] = e * in.att2[rel*128 + j];
  __syncthreads();
  for (int s=64; s>0; s>>=1){ if (j < s) red[j] += red[j+s]; __syncthreads(); }
  if (j == 0) w.logit2[i] = red[0];
}

// K5c: layer-2 softmax + aggregate + relu, then classifier head -> d_out[3].
// Only ~5 KB of global reads; single block is fine here.
__global__ void k5c_final(Inputs in, WSP w, float* outp){
  __shared__ float x2[128];
  __shared__ float tt[128];
  int j = threadIdx.x; // 128
  int n2 = w.cnt[0] < N2MAX ? w.cnt[0] : N2MAX;
  float o = 0.f;
  for (int r=2; r<=5; r++){
    o += in.bias2[r*128 + j];
    float m = -INFINITY;
    for (int i=0;i<n2;i++) if (w.l2rel[i]==r) m = fmaxf(m, w.logit2[i]);
    if (m == -INFINITY) continue;
    float d = 0.f, acc = 0.f;
    for (int i=0;i<n2;i++) if (w.l2rel[i]==r){
      float e = expf(w.logit2[i] - m);
      d += e;
      acc = fmaf(e, w.xl2e[(size_t)i*128 + j], acc);
    }
    o += acc/(d + 1e-16f);
  }
  x2[j] = fmaxf(o, 0.f);
  __syncthreads();
  float acc = in.bc1[j];
  for (int c=0;c<128;c++) acc = fmaf(x2[c], in.Wc1[c*128 + j], acc);
  tt[j] = fmaxf(acc, 0.f);
  __syncthreads();
  if (j < 3){
    float r = in.bc2[j];
    for (int c=0;c<128;c++) r = fmaf(tt[c], in.Wc2[c*3 + j], r);
    outp[j] = r;
  }
}

extern "C" void kernel_launch(void* const* d_in, const int* in_sizes, int n_in,
                              void* d_out, int out_size, void* d_ws, size_t ws_size,
                              hipStream_t stream){
  Inputs in;
  in.x_asset   = (const float*)d_in[0];
  in.x_creator = (const float*)d_in[1];
  in.x_licensee= (const float*)d_in[2];
  Edges eg;
  eg.cb_s =(const int*)d_in[3];  eg.cb_d =(const int*)d_in[4];  eg.ea_cb =(const float*)d_in[5];  eg.Ecb = in_sizes[3];
  eg.lt_s =(const int*)d_in[6];  eg.lt_d =(const int*)d_in[7];  eg.ea_lt =(const float*)d_in[8];  eg.Elt = in_sizes[6];
  eg.sim_s=(const int*)d_in[9];  eg.sim_d=(const int*)d_in[10]; eg.ea_sim=(const float*)d_in[11]; eg.Esim= in_sizes[9];
  eg.fw_s =(const int*)d_in[12]; eg.fw_d =(const int*)d_in[13]; eg.ea_fw =(const float*)d_in[14]; eg.Efw = in_sizes[12];
  eg.rcb_s=(const int*)d_in[15]; eg.rcb_d=(const int*)d_in[16]; eg.ea_rcb=(const float*)d_in[17]; eg.Ercb= in_sizes[15];
  eg.rlt_s=(const int*)d_in[18]; eg.rlt_d=(const int*)d_in[19]; eg.ea_rlt=(const float*)d_in[20]; eg.Erlt= in_sizes[18];
  in.Wp_a=(const float*)d_in[21]; in.bp_a=(const float*)d_in[22];
  in.Wp_c=(const float*)d_in[23]; in.bp_c=(const float*)d_in[24];
  in.Wp_l=(const float*)d_in[25]; in.bp_l=(const float*)d_in[26];
  in.Wl1=(const float*)d_in[27]; in.bl1=(const float*)d_in[28];
  in.Wr1=(const float*)d_in[29]; in.br1=(const float*)d_in[30];
  in.We1=(const float*)d_in[31]; in.att1=(const float*)d_in[32]; in.bias1=(const float*)d_in[33];
  in.Wl2=(const float*)d_in[34]; in.bl2=(const float*)d_in[35];
  in.Wr2=(const float*)d_in[36]; in.br2=(const float*)d_in[37];
  in.We2=(const float*)d_in[38]; in.att2=(const float*)d_in[39]; in.bias2=(const float*)d_in[40];
  in.Wc1=(const float*)d_in[41]; in.bc1=(const float*)d_in[42];
  in.Wc2=(const float*)d_in[43]; in.bc2=(const float*)d_in[44];
  const int* qptr = (const int*)d_in[45];

  char* p = (char*)d_ws;
  auto carve = [&](size_t n)->char*{ char* r = p; p += ((n + 255) & ~(size_t)255); return r; };
  WSP w;
  w.cnt  = (int*)carve(16*4);
  w.fa = (int*)carve(FAMAX*4); w.fc = (int*)carve(FCMAX*4); w.fl = (int*)carve(FLMAX*4);
  w.l2rel=(int*)carve(N2MAX*4); w.l2src=(int*)carve(N2MAX*4); w.l2slot=(int*)carve(N2MAX*4); w.l2ea=(float*)carve(N2MAX*4);
  w.l1rel=(int*)carve(N1MAX*4); w.l1src=(int*)carve(N1MAX*4); w.l1dslot=(int*)carve(N1MAX*4); w.l1ea=(float*)carve(N1MAX*4);
  w.xl1e=(float*)carve((size_t)N1MAX*256*4);
  w.logit1=(float*)carve((size_t)N1MAX*2*4);
  w.x1a=(float*)carve((size_t)FAMAX*128*4);
  w.x1c=(float*)carve((size_t)FCMAX*128*4);
  w.x1l=(float*)carve((size_t)FLMAX*128*4);
  w.xl2e=(float*)carve((size_t)N2MAX*128*4);
  w.logit2=(float*)carve(N2MAX*4);

  hipMemsetAsync(w.cnt, 0, 16*4, stream);

  int tE2_4 = (eg.Esim + eg.Efw + eg.Ercb + eg.Erlt) >> 2;
  k1_scan_l2<<<(tE2_4+255)/256, 256, 0, stream>>>(eg, qptr, w);
  int tE1_4 = (eg.Ecb + eg.Elt + eg.Esim + eg.Efw + eg.Ercb + eg.Erlt) >> 2;
  k2_scan_l1<<<(tE1_4+255)/256, 256, 0, stream>>>(eg, w);
  k3_edge<<<N1MAX, 256, 0, stream>>>(in, w);
  k4_agg<<<FAMAX + FCMAX + FLMAX, 128, 0, stream>>>(in, w);
  k5b_l2edge<<<N2MAX, 128, 0, stream>>>(in, w);
  k5c_final<<<1, 128, 0, stream>>>(in, w, (float*)d_out);
}